// Round 1
// baseline (306.169 us; speedup 1.0000x reference)
//
#include <hip/hip_runtime.h>

#define B_      32
#define C_COMB  448
#define N_POS_  4096
#define D_      100

typedef __attribute__((ext_vector_type(8)))  short bf16x8;
typedef __attribute__((ext_vector_type(4)))  float f32x4;
typedef __attribute__((ext_vector_type(16))) float f32x16;

// ---------------- bf16 helpers (RNE) ----------------
__device__ __forceinline__ unsigned short f2bf(float f) {
    unsigned u = __builtin_bit_cast(unsigned, f);
    u += 0x7FFFu + ((u >> 16) & 1u);
    return (unsigned short)(u >> 16);
}
__device__ __forceinline__ unsigned pack2bf(float a, float b) {
    return (unsigned)f2bf(a) | ((unsigned)f2bf(b) << 16);
}
__device__ __forceinline__ float bf2f(unsigned short h) {
    return __builtin_bit_cast(float, (unsigned)h << 16);
}
__device__ __forceinline__ float4 bf4_to_f4(uint2 u) {
    float4 r;
    r.x = __builtin_bit_cast(float, u.x << 16);
    r.y = __builtin_bit_cast(float, u.x & 0xffff0000u);
    r.z = __builtin_bit_cast(float, u.y << 16);
    r.w = __builtin_bit_cast(float, u.y & 0xffff0000u);
    return r;
}
__device__ __forceinline__ bf16x8 pack8bf(float4 lo, float4 hi) {
    bf16x8 r;
    r[0] = (short)f2bf(lo.x); r[1] = (short)f2bf(lo.y);
    r[2] = (short)f2bf(lo.z); r[3] = (short)f2bf(lo.w);
    r[4] = (short)f2bf(hi.x); r[5] = (short)f2bf(hi.y);
    r[6] = (short)f2bf(hi.z); r[7] = (short)f2bf(hi.w);
    return r;
}

// async global->LDS, 16 B per lane, lane-linear LDS dest (wave-uniform base)
__device__ __forceinline__ void gl_lds16(const float* g, float* l) {
    __builtin_amdgcn_global_load_lds(
        (const __attribute__((address_space(1))) void*)g,
        (__attribute__((address_space(3))) void*)l, 16, 0, 0);
}

// ---------------------------------------------------------------------------
// Kernel 1: prep — W fp32 -> Wb bf16 (contiguous [100][448])
// ---------------------------------------------------------------------------
__global__ __launch_bounds__(256) void k_prep(const float* __restrict__ W,
                                              unsigned short* __restrict__ Wb) {
    int i = blockIdx.x * 256 + threadIdx.x;
    if (i < 11200) {                       // 44800 floats as f4
        float4 v = ((const float4*)W)[i];
        ((uint2*)Wb)[i] = make_uint2(pack2bf(v.x, v.y), pack2bf(v.z, v.w));
    }
}

// ---------------------------------------------------------------------------
// Kernel 2: fused projection GEMM (unchanged):
//   p32[pos][b][d] = sum_c W[d][c] * comb[b][c][pos] + bias[d]
// ---------------------------------------------------------------------------
__global__ __launch_bounds__(256) void k_proj(const float* __restrict__ comb,
                                              const unsigned short* __restrict__ Wb,
                                              const float* __restrict__ bias,
                                              unsigned short* __restrict__ p32b) {
    __shared__ float Tf[32 * 65];            // 8320 B, [cc][p] pad 65
    __shared__ unsigned short Ws[D_ * 40];   // 8000 B, [d][kk] pad 40

    const int pt = blockIdx.x, b = blockIdx.y;
    const int t = threadIdx.x;
    const int lane = t & 63, w = t >> 6;
    const int c = lane & 15, q = lane >> 4;

    f32x4 acc[7];
#pragma unroll
    for (int mt = 0; mt < 7; mt++) acc[mt] = (f32x4){0.f, 0.f, 0.f, 0.f};

    const float4* comb4 = (const float4*)comb;

    for (int kt = 0; kt < 14; kt++) {
        __syncthreads();
#pragma unroll
        for (int k = 0; k < 2; k++) {
            int e4 = t + 256 * k;
            int cc = e4 >> 4, p4 = e4 & 15;
            float4 v = comb4[((size_t)b * C_COMB + kt * 32 + cc) * 256 + pt * 16 + p4];
            Tf[cc * 65 + p4 * 4 + 0] = v.x;
            Tf[cc * 65 + p4 * 4 + 1] = v.y;
            Tf[cc * 65 + p4 * 4 + 2] = v.z;
            Tf[cc * 65 + p4 * 4 + 3] = v.w;
        }
#pragma unroll
        for (int k = 0; k < 4; k++) {
            int e = t + 256 * k;
            if (e < 800) {
                int d = e >> 3, c4 = e & 7;
                *(uint2*)(Ws + d * 40 + c4 * 4) =
                    *(const uint2*)(Wb + d * C_COMB + kt * 32 + c4 * 4);
            }
        }
        __syncthreads();

        bf16x8 bfrag;
#pragma unroll
        for (int j = 0; j < 8; j++) {
            bfrag[j] = (short)f2bf(Tf[(q * 8 + j) * 65 + w * 16 + c]);
        }
#pragma unroll
        for (int mt = 0; mt < 7; mt++) {
            int r = mt * 16 + c;
            bf16x8 afrag;
            if (r < D_) afrag = *(const bf16x8*)(Ws + r * 40 + q * 8);
            else        afrag = (bf16x8){0,0,0,0,0,0,0,0};
            acc[mt] = __builtin_amdgcn_mfma_f32_16x16x32_bf16(afrag, bfrag, acc[mt], 0, 0, 0);
        }
    }

    const int pos = pt * 64 + w * 16 + c;
#pragma unroll
    for (int mt = 0; mt < 7; mt++) {
        int d0 = mt * 16 + q * 4;
        if (d0 < D_) {
            f32x4 a = acc[mt];
            float o0 = a[0] + bias[d0 + 0];
            float o1 = a[1] + bias[d0 + 1];
            float o2 = a[2] + bias[d0 + 2];
            float o3 = a[3] + bias[d0 + 3];
            *(uint2*)(p32b + ((size_t)pos * B_ + b) * D_ + d0) =
                make_uint2(pack2bf(o0, o1), pack2bf(o2, o3));
        }
    }
}

// ---------------------------------------------------------------------------
// Kernel 3: per n: bilinear 32->64 of p32 (bf16), mean subtract, Mahalanobis.
// CHANGE vs R-prev: Sigma^-1 is now staged into LDS with coalesced
// global_load_lds (width 16, lane-linear dest). Previously each lane read
// its own 400-B-strided row directly from global -> every wave vmem op
// touched 32 distinct sectors (transaction-bound, ~0.65 TB/s effective).
// Row-major [100][100] fp32 LDS: row stride 400 B = 25 quad-banks == 1 mod 8
// -> ds_read_b128 fragments distribute evenly, no padding needed.
// LDS ~47.6 KB -> 3 blocks/CU, 12 waves: enough to pipeline stage->compute.
// ---------------------------------------------------------------------------
__global__ __launch_bounds__(256) void k_mahal(const unsigned short* __restrict__ p32b,
                                               const float* __restrict__ mean,
                                               const float* __restrict__ icov,
                                               float* __restrict__ gdist) {
    __shared__ float icovL[10000];             // 40000 B, [r][k] row-major
    __shared__ unsigned short dTb[B_ * 104];   // 6656 B, [32 b][104 k] bf16
    __shared__ float meanL[112];               // 100 used (16B-aligned reads)
    __shared__ float part[128];                // [4 waves][32 b]

    const int n = blockIdx.x;
    const int t = threadIdx.x;
    const int lane = t & 63, w = t >> 6;
    const int half = lane >> 5;                // k-half within wave
    const int l31  = lane & 31;

    // ---- stage Sigma^-1[n] into LDS: 2500 float4, coalesced, async ----
    const float* Msrc = icov + (size_t)n * (D_ * D_);
    {
        const int wbase = w * 64;              // wave-uniform
#pragma unroll
        for (int it = 0; it < 9; it++) {
            int idx = it * 256 + t;            // float4 index, lane-linear
            gl_lds16(Msrc + (size_t)idx * 4, icovL + (it * 256 + wbase) * 4);
        }
        int idx = 9 * 256 + t;
        if (idx < 2500) {
            gl_lds16(Msrc + (size_t)idx * 4, icovL + (9 * 256 + wbase) * 4);
        }
    }

    // mean[d][n] -> meanL (scalar, stride 16KB; L2-hot: each line reused by 64 n)
    if (t < 100) meanL[t] = mean[t * N_POS_ + n];
    if (t >= 128 && t < 160) *(uint2*)(dTb + (t - 128) * 104 + 100) = make_uint2(0u, 0u);

    // bilinear 32->64 source (half-pixel, clamp)
    const int y = n >> 6, x = n & 63;
    float sy = 0.5f * y - 0.25f, sx = 0.5f * x - 0.25f;
    float y0f = floorf(sy), x0f = floorf(sx);
    float fy = sy - y0f, fx = sx - x0f;
    int iy0 = max((int)y0f, 0), iy1 = min((int)y0f + 1, 31);
    int ix0 = max((int)x0f, 0), ix1 = min((int)x0f + 1, 31);
    const float w00 = (1.f - fy) * (1.f - fx), w01 = (1.f - fy) * fx;
    const float w10 = fy * (1.f - fx),         w11 = fy * fx;
    const unsigned short* s00 = p32b + (size_t)(iy0 * 32 + ix0) * 3200;
    const unsigned short* s01 = p32b + (size_t)(iy0 * 32 + ix1) * 3200;
    const unsigned short* s10 = p32b + (size_t)(iy1 * 32 + ix0) * 3200;
    const unsigned short* s11 = p32b + (size_t)(iy1 * 32 + ix1) * 3200;

    __syncthreads();   // meanL visible (also drains icov stage; other blocks overlap)

    // build dTb[b][d] bf16: 800 groups of 4 d
#pragma unroll
    for (int k = 0; k < 4; k++) {
        int e4 = t + 256 * k;
        if (e4 < 800) {
            int b  = e4 / 25;
            int d4 = e4 - b * 25;
            float4 f00 = bf4_to_f4(*(const uint2*)(s00 + e4 * 4));
            float4 f01 = bf4_to_f4(*(const uint2*)(s01 + e4 * 4));
            float4 f10 = bf4_to_f4(*(const uint2*)(s10 + e4 * 4));
            float4 f11 = bf4_to_f4(*(const uint2*)(s11 + e4 * 4));
            float4 m = *(const float4*)(meanL + d4 * 4);
            float vx = w00 * f00.x + w01 * f01.x + w10 * f10.x + w11 * f11.x - m.x;
            float vy = w00 * f00.y + w01 * f01.y + w10 * f10.y + w11 * f11.y - m.y;
            float vz = w00 * f00.z + w01 * f01.z + w10 * f10.z + w11 * f11.z - m.z;
            float vw = w00 * f00.w + w01 * f01.w + w10 * f10.w + w11 * f11.w - m.w;
            *(uint2*)(dTb + b * 104 + d4 * 4) =
                make_uint2(pack2bf(vx, vy), pack2bf(vz, vw));
        }
    }
    __syncthreads();   // dTb visible

    // ---- MFMA 32x32x16: Y[r][b]; wave w owns rows 32w..32w+31 ----
    // A layout: m = lane&31, k = (lane>>5)*8 + j
    const int r = 32 * w + l31;
    const bool rv = (r < D_);
    const float* MrowL = icovL + r * D_;

    f32x16 acc = {0.f,0.f,0.f,0.f,0.f,0.f,0.f,0.f,0.f,0.f,0.f,0.f,0.f,0.f,0.f,0.f};
#pragma unroll
    for (int kt = 0; kt < 7; kt++) {
        int k0 = kt * 16 + half * 8;
        bf16x8 afrag;
        if (rv && k0 < D_) {
            float4 lo = *(const float4*)(MrowL + k0);
            float4 hi;
            if (k0 + 4 < D_) hi = *(const float4*)(MrowL + k0 + 4);
            else             hi = (float4){0.f, 0.f, 0.f, 0.f};
            afrag = pack8bf(lo, hi);
        } else {
            afrag = (bf16x8){0,0,0,0,0,0,0,0};
        }
        bf16x8 bfrag;
        if (k0 < D_) bfrag = *(const bf16x8*)(dTb + l31 * 104 + k0);
        else         bfrag = (bf16x8){0,0,0,0,0,0,0,0};
        acc = __builtin_amdgcn_mfma_f32_32x32x16_bf16(afrag, bfrag, acc, 0, 0, 0);
    }

    // ---- fold: dist_b += Y[rr][b] * d[b][rr] over this wave's rows ----
    // C/D layout (verified m74/m101): col=lane&31, row=(reg&3)+8*(reg>>2)+4*(lane>>5)
    float dist = 0.f;
#pragma unroll
    for (int reg = 0; reg < 16; reg++) {
        int rr = 32 * w + (reg & 3) + 8 * (reg >> 2) + 4 * half;
        if (rr < D_) dist += acc[reg] * bf2f(dTb[l31 * 104 + rr]);
    }
    dist += __shfl_xor(dist, 32);
    if (half == 0) part[w * 32 + l31] = dist;
    __syncthreads();
    if (t < 32) {
        float s = part[t] + part[32 + t] + part[64 + t] + part[96 + t];
        gdist[t * N_POS_ + n] = s;
    }
}

// ---------------------------------------------------------------------------
// Kernel 4: 4x bilinear upsample 64->256 + normalize
// ---------------------------------------------------------------------------
__global__ __launch_bounds__(256) void k_upsample(const float* __restrict__ gdist,
                                                  const float* __restrict__ nminp,
                                                  const float* __restrict__ nmaxp,
                                                  float* __restrict__ out) {
    int gid = blockIdx.x * 256 + threadIdx.x;
    int b   = gid >> 16;
    int rem = gid & 65535;
    int Y = rem >> 8, X = rem & 255;
    float sy = 0.25f * Y - 0.375f, sx = 0.25f * X - 0.375f;
    float y0f = floorf(sy), x0f = floorf(sx);
    float fy = sy - y0f, fx = sx - x0f;
    int iy0 = max((int)y0f, 0), iy1 = min((int)y0f + 1, 63);
    int ix0 = max((int)x0f, 0), ix1 = min((int)x0f + 1, 63);
    const float* g = gdist + b * N_POS_;
    float v00 = g[iy0 * 64 + ix0], v01 = g[iy0 * 64 + ix1];
    float v10 = g[iy1 * 64 + ix0], v11 = g[iy1 * 64 + ix1];
    float v = (1.f - fy) * ((1.f - fx) * v00 + fx * v01)
            +        fy  * ((1.f - fx) * v10 + fx * v11);
    float nmin = nminp[0], nmax = nmaxp[0];
    float scale = 1.0f / (nmax - nmin + 1e-8f);
    out[gid] = (v - nmin) * scale;
}

// ---------------------------------------------------------------------------
extern "C" void kernel_launch(void* const* d_in, const int* in_sizes, int n_in,
                              void* d_out, int out_size, void* d_ws, size_t ws_size,
                              hipStream_t stream) {
    const float* comb = (const float*)d_in[0];
    const float* W    = (const float*)d_in[1];
    const float* bias = (const float*)d_in[2];
    const float* mean = (const float*)d_in[3];
    const float* icov = (const float*)d_in[4];
    const float* nmin = (const float*)d_in[5];
    const float* nmax = (const float*)d_in[6];
    float* out = (float*)d_out;

    char* ws = (char*)d_ws;
    unsigned short* p32b  = (unsigned short*)(ws);            //  6,553,600 B
    unsigned short* Wb    = (unsigned short*)(ws + 6553600);  //     89,600 B
    float*          gdist = (float*)(ws + 6643200);           //    524,288 B

    k_prep    <<<44, 256, 0, stream>>>(W, Wb);
    k_proj    <<<dim3(16, 32), 256, 0, stream>>>(comb, Wb, bias, p32b);
    k_mahal   <<<4096, 256, 0, stream>>>(p32b, mean, icov, gdist);
    k_upsample<<<8192, 256, 0, stream>>>(gdist, nmin, nmax, out);
}